// Round 5
// baseline (129.026 us; speedup 1.0000x reference)
//
#include <hip/hip_runtime.h>
#include <hip/hip_bf16.h>

#define BS 16
#define NQ 200
#define NPTS 25
#define VOC 96
#define VOCP1 97
#define NGT 32
#define LSEQ 25
#define NCOL (BS*NGT)      // 512
#define NBQ (BS*NQ)        // 3200
#define KL_EPS 1e-6f
#define FOCAL_EPS 1e-8f

#define NKA 1600           // kA-style blocks (2 bq rows each)
#define NSOFT 96
#define NKC 400            // 50 row-tiles x 8 col-tiles

// ================= L1: logP | soft | cdist+cc =================
// blocks [0,1600): two (b,q) logP rows each (tid<128 -> bq0, else bq1)
// blocks [1600,1696): soft_all row (i = idx-1600)
// blocks [1696,2096): 64x64 cdist tile + in-block focal class cost
__global__ __launch_bounds__(256) void L1(
        const float* __restrict__ pred_logits,       // [NBQ, 25]
        const float* __restrict__ pred_ctrl,         // [NBQ, 50]
        const float* __restrict__ pred_text_logits,  // [NBQ, 25, 97]
        const float* __restrict__ tgt_ctrl,          // [512, 50]
        const float* __restrict__ centroids,         // [96, 256]
        float* __restrict__ logP,                    // [NBQ, 96]
        float* __restrict__ soft,                    // [96, 96]
        float* __restrict__ out)                     // [NBQ, 512]
{
    __shared__ float smem[8320];   // 33.3 KB union
    const int tid = threadIdx.x;

    if (blockIdx.x < NKA) {
        // ---------- logP for bq = blockIdx.x*2 + half ----------
        float* s_buf    = smem;            // [2][2425]
        float* s_invden = smem + 4850;     // [2][25]
        float* s_part   = smem + 4900;     // [2][2]
        const int half = tid >> 7, htid = tid & 127;
        const int bq   = blockIdx.x * 2 + half;
        const int wv   = htid >> 6, lane = htid & 63;
        float* buf = s_buf + half * (NPTS * VOCP1);

        const float* tl = pred_text_logits + (size_t)bq * NPTS * VOCP1;
        for (int i = htid; i < NPTS * VOCP1; i += 128)
            buf[i] = __expf(tl[i]);
        __syncthreads();

        // per-point softmax denominators: 4 subgroups of 32 per half
        const int grp = htid >> 5, sub = htid & 31;
        for (int p0 = 0; p0 < NPTS; p0 += 4) {
            int p = p0 + grp;
            float s = 0.f;
            if (p < NPTS)
                for (int v = sub; v < VOCP1; v += 32) s += buf[p * VOCP1 + v];
            #pragma unroll
            for (int off = 16; off; off >>= 1) s += __shfl_xor(s, off, 32);
            if (p < NPTS && sub == 0) s_invden[half * NPTS + p] = 1.0f / s;
        }
        __syncthreads();

        float avg = 0.f;
        if (htid < VOC) {
            float a = 0.f;
            #pragma unroll
            for (int p = 0; p < NPTS; p++)
                a += buf[p * VOCP1 + htid] * s_invden[half * NPTS + p];
            avg = a * (1.0f / NPTS);
        }
        float s = avg;
        #pragma unroll
        for (int off = 32; off; off >>= 1) s += __shfl_xor(s, off);
        if (lane == 0) s_part[half * 2 + wv] = s;
        __syncthreads();
        float denom = s_part[half * 2] + s_part[half * 2 + 1] + (float)VOC * KL_EPS;
        if (htid < VOC)
            logP[(size_t)bq * VOC + htid] = __logf((avg + KL_EPS) / denom);

    } else if (blockIdx.x < NKA + NSOFT) {
        // ---------- soft_all row i ----------
        const int i = blockIdx.x - NKA;
        float* s_row  = smem;          // [256]
        float* s_part = smem + 256;    // [4]
        if (tid < 64)
            *(float4*)&s_row[tid * 4] = *(const float4*)&centroids[i * 256 + tid * 4];
        __syncthreads();

        float e = 0.f;
        if (tid < VOC) {
            float dij = 0.f, djj = 0.f, dii = 0.f;
            const float4* cj = (const float4*)(centroids + (size_t)tid * 256);
            #pragma unroll 4
            for (int k = 0; k < 64; k++) {
                float4 b = cj[k];
                float4 a = *(const float4*)&s_row[k * 4];
                dij += a.x * b.x + a.y * b.y + a.z * b.z + a.w * b.w;
                djj += b.x * b.x + b.y * b.y + b.z * b.z + b.w * b.w;
                dii += a.x * a.x + a.y * a.y + a.z * a.z + a.w * a.w;
            }
            e = __expf(dij * rsqrtf(dii * djj));
        }
        const int wv = tid >> 6, lane = tid & 63;
        float s = e;
        #pragma unroll
        for (int off = 32; off; off >>= 1) s += __shfl_xor(s, off);
        if (lane == 0) s_part[wv] = s;
        __syncthreads();
        float den = s_part[0] + s_part[1] + s_part[2] + s_part[3];
        if (tid < VOC) {
            float v = 0.15f * e / den;
            if (tid == i) v += 0.85f;
            soft[i * VOC + tid] = v;
        }
    } else {
        // ---------- 64x64 cdist tile + in-block cc ----------
        const int bid = blockIdx.x - (NKA + NSOFT);
        const int r0  = (bid >> 3) * 64;
        const int c0  = (bid & 7) * 64;
        float* s_p  = smem;            // [64][52]
        float* s_t  = smem + 3328;     // [64][52]
        float* s_cl = smem + 6656;     // [1600] class logits
        float* s_cc = smem + 8256;     // [64]

        const float* pg = pred_ctrl + (size_t)r0 * 50;
        const float* tg = tgt_ctrl + (size_t)c0 * 50;
        for (int i = tid; i < 64 * 50; i += 256) {
            int r = i / 50, d = i - r * 50;
            s_p[r * 52 + d] = pg[i];
            s_t[r * 52 + d] = tg[i];
        }
        for (int i = tid; i < 64 * NPTS; i += 256)
            s_cl[i] = pred_logits[(size_t)r0 * NPTS + i];
        __syncthreads();

        if (tid < 64) {   // focal class cost for row tid
            float s = 0.f;
            #pragma unroll
            for (int l = 0; l < NPTS; l++) {
                float x = s_cl[tid * NPTS + l];
                float p = 1.f / (1.f + __expf(-x));
                float pos = 0.25f * (1.f - p) * (1.f - p) * (-__logf(p + FOCAL_EPS));
                float neg = 0.75f * p * p * (-__logf(1.f - p + FOCAL_EPS));
                s += pos - neg;
            }
            s_cc[tid] = s * (1.0f / NPTS);
        }
        __syncthreads();

        const int tx = tid & 15, ty = tid >> 4;
        float acc[4][4];
        #pragma unroll
        for (int i = 0; i < 4; i++)
            #pragma unroll
            for (int j = 0; j < 4; j++) acc[i][j] = 0.f;

        #pragma unroll
        for (int k = 0; k < 48; k += 4) {
            float4 p[4], t[4];
            #pragma unroll
            for (int i = 0; i < 4; i++) p[i] = *(const float4*)&s_p[(ty * 4 + i) * 52 + k];
            #pragma unroll
            for (int j = 0; j < 4; j++) t[j] = *(const float4*)&s_t[(tx + 16 * j) * 52 + k];
            #pragma unroll
            for (int i = 0; i < 4; i++)
                #pragma unroll
                for (int j = 0; j < 4; j++)
                    acc[i][j] += fabsf(p[i].x - t[j].x) + fabsf(p[i].y - t[j].y)
                               + fabsf(p[i].z - t[j].z) + fabsf(p[i].w - t[j].w);
        }
        {   // k = 48, 49
            float2 p[4], t[4];
            #pragma unroll
            for (int i = 0; i < 4; i++) p[i] = *(const float2*)&s_p[(ty * 4 + i) * 52 + 48];
            #pragma unroll
            for (int j = 0; j < 4; j++) t[j] = *(const float2*)&s_t[(tx + 16 * j) * 52 + 48];
            #pragma unroll
            for (int i = 0; i < 4; i++)
                #pragma unroll
                for (int j = 0; j < 4; j++)
                    acc[i][j] += fabsf(p[i].x - t[j].x) + fabsf(p[i].y - t[j].y);
        }

        #pragma unroll
        for (int i = 0; i < 4; i++) {
            const int row = ty * 4 + i;
            const float cc = s_cc[row];
            #pragma unroll
            for (int j = 0; j < 4; j++)
                out[(size_t)(r0 + row) * NCOL + c0 + tx + 16 * j] = acc[i][j] + cc;
        }
    }
}

// ================= L2: in-block T + KL text cost (RMW diag block) =========
__global__ __launch_bounds__(256) void L2(
        const float* __restrict__ logP,      // [NBQ, 96]
        const float* __restrict__ soft,      // [96, 96]
        const int* __restrict__ tgt_texts,   // [512, 25]
        float* __restrict__ out)             // [NBQ, 512]
{
    const int r0  = blockIdx.x * 8;     // 8 | 200: no batch crossing
    const int b   = r0 / NQ;
    const int tid = threadIdx.x;
    __shared__ float s_soft[VOC * VOC];        // 36.9 KB
    __shared__ float s_lp[8][VOC];
    __shared__ float s_Tt[VOC][NGT + 1];       // transposed T
    __shared__ float s_tl[NGT];
    __shared__ int   s_len[NGT];
    __shared__ int   s_chars[NGT][LSEQ];

    for (int i = tid; i < VOC * VOC / 4; i += 256)
        ((float4*)s_soft)[i] = ((const float4*)soft)[i];
    for (int i = tid; i < 8 * VOC; i += 256)
        s_lp[i / VOC][i % VOC] = logP[(size_t)r0 * VOC + i];
    for (int i = tid; i < NGT * LSEQ; i += 256)
        s_chars[i / LSEQ][i % LSEQ] = tgt_texts[b * NGT * LSEQ + i];
    __syncthreads();

    // T rows for this batch: 8 groups of 32 lanes, 3 v's per lane
    const int grp = tid >> 5, sub = tid & 31;
    for (int g = grp; g < NGT; g += 8) {
        int len = 0;
        float a0 = 0.f, a1 = 0.f, a2 = 0.f;
        for (int l = 0; l < LSEQ; l++) {
            int t = s_chars[g][l];
            if (t != VOC) {
                len++;
                const float* sr = s_soft + t * VOC;
                a0 += sr[sub]; a1 += sr[sub + 32]; a2 += sr[sub + 64];
            }
        }
        float inv = 1.f / (float)(len > 0 ? len : 1);
        a0 *= inv; a1 *= inv; a2 *= inv;
        float s = a0 + a1 + a2;
        #pragma unroll
        for (int off = 16; off; off >>= 1) s += __shfl_xor(s, off, 32);
        float denom = s + (float)VOC * KL_EPS;
        float t0 = (a0 + KL_EPS) / denom;
        float t1 = (a1 + KL_EPS) / denom;
        float t2 = (a2 + KL_EPS) / denom;
        s_Tt[sub][g]      = t0;
        s_Tt[sub + 32][g] = t1;
        s_Tt[sub + 64][g] = t2;
        float tl = t0 * __logf(t0) + t1 * __logf(t1) + t2 * __logf(t2);
        #pragma unroll
        for (int off = 16; off; off >>= 1) tl += __shfl_xor(tl, off, 32);
        if (sub == 0) { s_tl[g] = tl; s_len[g] = len; }
    }
    __syncthreads();

    const int g = tid & 31, rs = tid >> 5;
    float d = 0.f;
    #pragma unroll 8
    for (int v = 0; v < VOC; v++) d += s_lp[rs][v] * s_Tt[v][g];
    float val = (s_len[g] == 0) ? 100.f : (s_tl[g] - d);
    out[(size_t)(r0 + rs) * NCOL + b * NGT + g] += val;
}

extern "C" void kernel_launch(void* const* d_in, const int* in_sizes, int n_in,
                              void* d_out, int out_size, void* d_ws, size_t ws_size,
                              hipStream_t stream) {
    const float* pred_logits = (const float*)d_in[0];
    const float* pred_ctrl   = (const float*)d_in[1];
    const float* pred_text   = (const float*)d_in[2];
    const float* tgt_ctrl    = (const float*)d_in[3];
    const int*   tgt_texts   = (const int*)d_in[4];
    const float* centroids   = (const float*)d_in[5];
    float* out = (float*)d_out;

    float* ws   = (float*)d_ws;
    float* logP = ws;                          // 3200*96 floats (16B aligned)
    float* soft = logP + (size_t)NBQ * VOC;    // 96*96

    L1<<<NKA + NSOFT + NKC, 256, 0, stream>>>(
        pred_logits, pred_ctrl, pred_text, tgt_ctrl, centroids,
        logP, soft, out);
    L2<<<NKC, 256, 0, stream>>>(logP, soft, tgt_texts, out);
}